// Round 4
// baseline (147.664 us; speedup 1.0000x reference)
//
#include <hip/hip_runtime.h>
#include <math.h>

#define NB    4
#define NPTS  4096
#define BN    (NB * NPTS)
#define BLOCK 256
#define IT    4                    // queries per thread
#define QPB   (BLOCK * IT)         // 1024 queries per block
#define NQB   (NPTS / QPB)         // 4 qblocks per batch
#define NQG   (NB * NQB)           // 16 qblocks total

__device__ inline float wave_sum(float v) {
#pragma unroll
    for (int o = 32; o > 0; o >>= 1) v += __shfl_xor(v, o);
    return v;
}

// Block-wide (256-thread) sum; result broadcast. Caller ensures uniform entry.
__device__ inline float block_sum_256(float v, float* sbuf) {
    int lane = threadIdx.x & 63, w = threadIdx.x >> 6;
    v = wave_sum(v);
    __syncthreads();
    if (lane == 0) sbuf[w] = v;
    __syncthreads();
    return sbuf[0] + sbuf[1] + sbuf[2] + sbuf[3];
}

__global__ __launch_bounds__(64) void init_kernel(unsigned int* __restrict__ cnt) {
    if (threadIdx.x < NQG + 1) cnt[threadIdx.x] = 0;
}

// One fused kernel: per-chunk NN partial min -> (last block per qblock) combine +
// exp partial -> (last combine winner) centroid/variance/final scalar + counter reset.
template <int NJ>
__global__ __launch_bounds__(256) void mega_kernel(const float* __restrict__ pc,
                                                   unsigned int* __restrict__ cnt,
                                                   float* __restrict__ cpart,
                                                   float* __restrict__ qes,
                                                   float* __restrict__ pmin,
                                                   float* __restrict__ out) {
    constexpr int JC = NPTS / NJ;
    __shared__ float4 lpt[JC];
    __shared__ float sbuf[4];
    __shared__ float cen[NB][3];
    __shared__ unsigned int s_old, s_oldg;

    int blk = blockIdx.x;
    int jc  = blk % NJ;
    int qb  = blk / NJ;            // 0..15
    int b   = qb >> 2;             // batch
    int iq0 = (qb & 3) * QPB;
    int jbase = jc * JC;
    const float* p = pc + (size_t)b * NPTS * 3;
    int t = threadIdx.x;

    // ---- stage A: chunk into LDS as (x,y,z,|x|^2) ----
    for (int j = t; j < JC; j += BLOCK) {
        int jg = jbase + j;
        float x = p[3*jg+0], y = p[3*jg+1], z = p[3*jg+2];
        lpt[j] = make_float4(x, y, z, fmaf(x, x, fmaf(y, y, z * z)));
    }

    float ax[IT], ay[IT], az[IT], m[IT];
#pragma unroll
    for (int k = 0; k < IT; ++k) {
        int i = iq0 + t + k * BLOCK;
        ax[k] = -2.f * p[3*i+0];
        ay[k] = -2.f * p[3*i+1];
        az[k] = -2.f * p[3*i+2];
        m[k] = 1e30f;
    }
    __syncthreads();

    if ((jbase >> 10) == (qb & 3)) {           // chunk overlaps this block's queries
        int idl[IT];
#pragma unroll
        for (int k = 0; k < IT; ++k) idl[k] = iq0 + t + k * BLOCK - jbase;
#pragma unroll 4
        for (int j = 0; j < JC; ++j) {
            float4 q = lpt[j];
#pragma unroll
            for (int k = 0; k < IT; ++k) {
                float e = fmaf(ax[k], q.x, fmaf(ay[k], q.y, fmaf(az[k], q.z, q.w)));
                m[k] = fminf(m[k], (j == idl[k]) ? 1e30f : e);
            }
        }
    } else {
#pragma unroll 8
        for (int j = 0; j < JC; j += 2) {      // paired -> v_min3 fusion
            float4 q0 = lpt[j], q1 = lpt[j+1];
#pragma unroll
            for (int k = 0; k < IT; ++k) {
                float e0 = fmaf(ax[k], q0.x, fmaf(ay[k], q0.y, fmaf(az[k], q0.z, q0.w)));
                float e1 = fmaf(ax[k], q1.x, fmaf(ay[k], q1.y, fmaf(az[k], q1.z, q1.w)));
                m[k] = fminf(fminf(m[k], e0), e1);
            }
        }
    }

#pragma unroll
    for (int k = 0; k < IT; ++k)
        pmin[(size_t)jc * BN + b * NPTS + iq0 + t + k * BLOCK] = m[k];

    // centroid partials for this qblock (jc==0 blocks only; block-uniform branch)
    if (jc == 0) {
        float sx = 0.f, sy = 0.f, sz = 0.f;
#pragma unroll
        for (int k = 0; k < IT; ++k) { sx += ax[k]; sy += ay[k]; sz += az[k]; }
        float tx = block_sum_256(sx, sbuf);
        float ty = block_sum_256(sy, sbuf);
        float tz = block_sum_256(sz, sbuf);
        if (t == 0) {
            cpart[qb * 3 + 0] = -0.5f * tx;    // undo -2 prefold
            cpart[qb * 3 + 1] = -0.5f * ty;
            cpart[qb * 3 + 2] = -0.5f * tz;
        }
    }

    // ---- release + elect per-qblock combine winner ----
    __threadfence();
    __syncthreads();
    if (t == 0) s_old = atomicAdd(&cnt[qb], 1u);
    __syncthreads();
    if (s_old != NJ - 1) return;

    // ---- stage B: combine mins for this qblock's 1024 queries, exp partial ----
    __threadfence();                            // acquire
    float es = 0.f;
    int gg[IT];
    float mm[IT];
#pragma unroll
    for (int k = 0; k < IT; ++k) {
        gg[k] = b * NPTS + iq0 + t + k * BLOCK;
        mm[k] = pmin[gg[k]];
    }
#pragma unroll 8
    for (int jcc = 1; jcc < NJ; ++jcc) {
#pragma unroll
        for (int k = 0; k < IT; ++k)
            mm[k] = fminf(mm[k], pmin[(size_t)jcc * BN + gg[k]]);
    }
#pragma unroll
    for (int k = 0; k < IT; ++k) {
        int i = iq0 + t + k * BLOCK;
        float x = p[3*i+0], y = p[3*i+1], z = p[3*i+2];
        float ri = fmaf(x, x, fmaf(y, y, z * z));
        es += __expf(-5.f * fmaxf(ri + mm[k], 0.f));
    }
    float es_blk = block_sum_256(es, sbuf);
    if (t == 0) qes[qb] = es_blk;

    // ---- release + elect global finisher ----
    __threadfence();
    __syncthreads();
    if (t == 0) s_oldg = atomicAdd(&cnt[NQG], 1u);
    __syncthreads();
    if (s_oldg != NQG - 1) return;

    // ---- stage C: centroids, variance, final scalar, counter reset ----
    __threadfence();                            // acquire
    if (t < NB) {
        float cx = 0.f, cy = 0.f, cz = 0.f;
#pragma unroll
        for (int q = 0; q < NQB; ++q) {
            cx += cpart[(t * NQB + q) * 3 + 0];
            cy += cpart[(t * NQB + q) * 3 + 1];
            cz += cpart[(t * NQB + q) * 3 + 2];
        }
        cen[t][0] = cx * (1.f / NPTS);
        cen[t][1] = cy * (1.f / NPTS);
        cen[t][2] = cz * (1.f / NPTS);
    }
    __syncthreads();

    float s1[NB], s2[NB];
#pragma unroll
    for (int bb = 0; bb < NB; ++bb) { s1[bb] = 0.f; s2[bb] = 0.f; }
#pragma unroll
    for (int i = 0; i < BN / BLOCK; ++i) {      // 64 iters, bb compile-time
        int g = i * BLOCK + t;
        int bb = i >> 4;
        float x = pc[3*g+0], y = pc[3*g+1], z = pc[3*g+2];
        float dx = x - cen[bb][0], dy = y - cen[bb][1], dz = z - cen[bb][2];
        float d2 = fmaf(dx, dx, fmaf(dy, dy, dz * dz));
        s1[bb] += sqrtf(d2);
        s2[bb] += d2;
    }

    float tot[2 * NB];
#pragma unroll
    for (int bb = 0; bb < NB; ++bb) {
        tot[2*bb]   = block_sum_256(s1[bb], sbuf);
        tot[2*bb+1] = block_sum_256(s2[bb], sbuf);
    }

    if (t == 0) {
        float es_tot = 0.f;
#pragma unroll
        for (int q = 0; q < NQG; ++q) es_tot += qes[q];
        float vsum = 0.f;
#pragma unroll
        for (int bb = 0; bb < NB; ++bb) {
            float S1 = tot[2*bb], S2 = tot[2*bb+1];
            vsum += (S2 - S1 * S1 * (1.f / NPTS)) * (1.f / (NPTS - 1));
        }
        out[0] = vsum * (1.f / NB) + es_tot * (1.f / BN);
    }
    // reset counters for the next replay (ws is not re-poisoned between replays)
    if (t <= NQG) cnt[t] = 0;
}

template <int NJ>
static void run(const float* pc, float* out, void* d_ws, hipStream_t stream) {
    unsigned int* cnt = (unsigned int*)d_ws;
    float* cpart = (float*)((char*)d_ws + 256);
    float* qes   = (float*)((char*)d_ws + 512);
    float* pmin  = (float*)((char*)d_ws + 1024);
    init_kernel<<<1, 64, 0, stream>>>(cnt);
    mega_kernel<NJ><<<NQG * NJ, BLOCK, 0, stream>>>(pc, cnt, cpart, qes, pmin, out);
}

extern "C" void kernel_launch(void* const* d_in, const int* in_sizes, int n_in,
                              void* d_out, int out_size, void* d_ws, size_t ws_size,
                              hipStream_t stream) {
    const float* pc = (const float*)d_in[0];
    float* out = (float*)d_out;
    auto need = [](int nj) { return (size_t)nj * BN * sizeof(float) + 1024; };

    if      (ws_size >= need(64)) run<64>(pc, out, d_ws, stream);
    else if (ws_size >= need(16)) run<16>(pc, out, d_ws, stream);
    else                          run<4> (pc, out, d_ws, stream);
}

// Round 5
// 25.906 us; speedup vs baseline: 5.6999x; 5.6999x over previous
//
#include <hip/hip_runtime.h>
#include <math.h>

#define NB    4
#define NPTS  4096
#define BN    (NB * NPTS)
#define BLOCK 256
#define IT    4                    // queries per thread
#define QPB   (BLOCK * IT)         // 1024 queries per block
#define NQB   (NPTS / QPB)         // 4 qblocks per batch

__device__ inline float wave_sum(float v) {
#pragma unroll
    for (int o = 32; o > 0; o >>= 1) v += __shfl_xor(v, o);
    return v;
}

// --- Kernel 1: per-chunk NN partial min (gram form, no ri) + centroid partials ---
// grid = 16 qblocks * NJ chunks. Plain stores -> no memset, no atomics, no fences.
template <int NJ>
__global__ __launch_bounds__(256) void nn_kernel(const float* __restrict__ pc,
                                                 float* __restrict__ pmin,
                                                 float* __restrict__ cpart) {
    constexpr int JC = NPTS / NJ;
    __shared__ float4 lpt[JC];
    __shared__ float sbuf[4];

    int blk = blockIdx.x;
    int jc  = blk % NJ;
    int qb  = blk / NJ;            // 0..15 global query block
    int b   = qb >> 2;             // batch (NQB=4 qblocks per batch)
    int iq0 = (qb & 3) * QPB;
    int jbase = jc * JC;
    const float* p = pc + (size_t)b * NPTS * 3;
    int t = threadIdx.x;

    // stage chunk: (x, y, z, |x|^2)
    if (t < JC) {
        int jg = jbase + t;
        float x = p[3*jg+0], y = p[3*jg+1], z = p[3*jg+2];
        lpt[t] = make_float4(x, y, z, fmaf(x, x, fmaf(y, y, z * z)));
    }

    // 4 query points, prefolded as (-2x, -2y, -2z)
    float ax[IT], ay[IT], az[IT], m[IT];
#pragma unroll
    for (int k = 0; k < IT; ++k) {
        int i = iq0 + t + k * BLOCK;
        ax[k] = -2.f * p[3*i+0];
        ay[k] = -2.f * p[3*i+1];
        az[k] = -2.f * p[3*i+2];
        m[k] = 1e30f;
    }
    __syncthreads();

    if ((jbase / QPB) == (qb & (NQB - 1))) {    // chunk overlaps this block's queries
        int idl[IT];
#pragma unroll
        for (int k = 0; k < IT; ++k) idl[k] = iq0 + t + k * BLOCK - jbase;
#pragma unroll 4
        for (int j = 0; j < JC; ++j) {
            float4 q = lpt[j];
#pragma unroll
            for (int k = 0; k < IT; ++k) {
                float e = fmaf(ax[k], q.x, fmaf(ay[k], q.y, fmaf(az[k], q.z, q.w)));
                m[k] = fminf(m[k], (j == idl[k]) ? 1e30f : e);
            }
        }
    } else {
#pragma unroll 8
        for (int j = 0; j < JC; j += 2) {       // paired -> v_min3 fusion
            float4 q0 = lpt[j], q1 = lpt[j+1];
#pragma unroll
            for (int k = 0; k < IT; ++k) {
                float e0 = fmaf(ax[k], q0.x, fmaf(ay[k], q0.y, fmaf(az[k], q0.z, q0.w)));
                float e1 = fmaf(ax[k], q1.x, fmaf(ay[k], q1.y, fmaf(az[k], q1.z, q1.w)));
                m[k] = fminf(fminf(m[k], e0), e1);
            }
        }
    }

#pragma unroll
    for (int k = 0; k < IT; ++k)
        pmin[(size_t)jc * BN + b * NPTS + iq0 + t + k * BLOCK] = m[k];

    // centroid partials: one chunk per qblock does it (queries already in regs, as -2x)
    if (jc == 0) {
        float sx = 0.f, sy = 0.f, sz = 0.f;
#pragma unroll
        for (int k = 0; k < IT; ++k) { sx += ax[k]; sy += ay[k]; sz += az[k]; }
        int lane = t & 63, w = t >> 6;
        sx = wave_sum(sx); sy = wave_sum(sy); sz = wave_sum(sz);
        __syncthreads();
        if (lane == 0) sbuf[w] = sx;
        __syncthreads();
        float tx = sbuf[0] + sbuf[1] + sbuf[2] + sbuf[3];
        __syncthreads();
        if (lane == 0) sbuf[w] = sy;
        __syncthreads();
        float ty = sbuf[0] + sbuf[1] + sbuf[2] + sbuf[3];
        __syncthreads();
        if (lane == 0) sbuf[w] = sz;
        __syncthreads();
        float tz = sbuf[0] + sbuf[1] + sbuf[2] + sbuf[3];
        if (t == 0) {
            cpart[qb * 3 + 0] = -0.5f * tx;    // undo the -2 prefold
            cpart[qb * 3 + 1] = -0.5f * ty;
            cpart[qb * 3 + 2] = -0.5f * tz;
        }
    }
}

// --- Kernel 2: parallel combine: min over chunks, exp penalty, variance parts ---
// grid = 64 blocks * 256 threads = one thread per query.
template <int NJ>
__global__ __launch_bounds__(256) void combine_kernel(const float* __restrict__ pc,
                                                      const float* __restrict__ pmin,
                                                      const float* __restrict__ cpart,
                                                      float* __restrict__ bpart) {
    __shared__ float sbuf[4];
    int blk = blockIdx.x;          // 0..63 (16 per batch)
    int b   = blk >> 4;
    int t   = threadIdx.x;
    int g   = blk * BLOCK + t;     // global query index

    float cx = 0.f, cy = 0.f, cz = 0.f;
#pragma unroll
    for (int q = 0; q < NQB; ++q) {
        cx += cpart[(b * NQB + q) * 3 + 0];
        cy += cpart[(b * NQB + q) * 3 + 1];
        cz += cpart[(b * NQB + q) * 3 + 2];
    }
    cx *= (1.f / NPTS); cy *= (1.f / NPTS); cz *= (1.f / NPTS);

    float m = fminf(pmin[g], pmin[(size_t)1 * BN + g]);
#pragma unroll 8
    for (int jc = 2; jc < NJ; jc += 2) {
        float a0 = pmin[(size_t)jc * BN + g];
        float a1 = pmin[(size_t)(jc + 1) * BN + g];
        m = fminf(fminf(m, a0), a1);
    }

    float x = pc[3*g+0], y = pc[3*g+1], z = pc[3*g+2];
    float ri = fmaf(x, x, fmaf(y, y, z * z));
    float mm = fmaxf(ri + m, 0.f);             // = max(||xi||^2 + min_j(rj - 2xi.xj), 0)
    float es = __expf(-5.f * mm);

    float dx = x - cx, dy = y - cy, dz = z - cz;
    float d2 = fmaf(dx, dx, fmaf(dy, dy, dz * dz));
    float vals[3] = { sqrtf(d2), d2, es };

    int lane = t & 63, w = t >> 6;
    float tot[3];
#pragma unroll
    for (int r = 0; r < 3; ++r) {
        float v = wave_sum(vals[r]);
        __syncthreads();
        if (lane == 0) sbuf[w] = v;
        __syncthreads();
        tot[r] = sbuf[0] + sbuf[1] + sbuf[2] + sbuf[3];
    }
    if (t == 0) {
        bpart[blk * 3 + 0] = tot[0];           // sum |x - c|
        bpart[blk * 3 + 1] = tot[1];           // sum |x - c|^2
        bpart[blk * 3 + 2] = tot[2];           // sum exp(-5 m)
    }
}

// --- Kernel 3: one wave: variance per batch, final scalar ---
__global__ __launch_bounds__(64) void finish_kernel(const float* __restrict__ bpart,
                                                    float* __restrict__ out) {
    int t = threadIdx.x;           // 64 block-partials, 16 per batch
    float s1 = bpart[t*3+0], s2 = bpart[t*3+1], es = bpart[t*3+2];
    float g1 = s1, g2 = s2;
#pragma unroll
    for (int o = 1; o < 16; o <<= 1) {
        g1 += __shfl_xor(g1, o);
        g2 += __shfl_xor(g2, o);
    }
    float et = es;
#pragma unroll
    for (int o = 1; o < 64; o <<= 1) et += __shfl_xor(et, o);

    float vs = 0.f;
#pragma unroll
    for (int b = 0; b < NB; ++b) {
        float S1 = __shfl(g1, b * 16);
        float S2 = __shfl(g2, b * 16);
        vs += (S2 - S1 * S1 * (1.f / NPTS)) * (1.f / (NPTS - 1));
    }
    if (t == 0) out[0] = vs * (1.f / NB) + et * (1.f / BN);
}

template <int NJ>
static void run(const float* pc, float* out, void* d_ws, hipStream_t stream) {
    float* pmin  = (float*)d_ws;
    float* cpart = (float*)((char*)d_ws + (size_t)NJ * BN * sizeof(float));
    float* bpart = cpart + 64;
    nn_kernel<NJ><<<16 * NJ, BLOCK, 0, stream>>>(pc, pmin, cpart);
    combine_kernel<NJ><<<64, BLOCK, 0, stream>>>(pc, pmin, cpart, bpart);
    finish_kernel<<<1, 64, 0, stream>>>(bpart, out);
}

extern "C" void kernel_launch(void* const* d_in, const int* in_sizes, int n_in,
                              void* d_out, int out_size, void* d_ws, size_t ws_size,
                              hipStream_t stream) {
    const float* pc = (const float*)d_in[0];
    float* out = (float*)d_out;
    auto need = [](int nj) { return (size_t)nj * BN * sizeof(float) + 4096; };

    if      (ws_size >= need(128)) run<128>(pc, out, d_ws, stream);
    else if (ws_size >= need(64))  run<64> (pc, out, d_ws, stream);
    else if (ws_size >= need(32))  run<32> (pc, out, d_ws, stream);
    else if (ws_size >= need(8))   run<8>  (pc, out, d_ws, stream);
    else                           run<4>  (pc, out, d_ws, stream);
}

// Round 6
// 16.336 us; speedup vs baseline: 9.0390x; 1.5858x over previous
//
#include <hip/hip_runtime.h>
#include <math.h>

#define NB    4
#define NPTS  4096
#define BN    (NB * NPTS)
#define TPB   512                 // 8 waves
#define QPB   64                  // queries per block
#define NBLK  (BN / QPB)          // 256 blocks -> 1 per CU
#define G     32                  // j-groups per block
#define JG    (NPTS / G)          // 128 j per group
#define IT    4                   // queries per thread
#define QCOLS (QPB / IT)          // 16 query-columns
#define NW    (TPB / 64)          // 8 waves

__device__ inline float wave_sum(float v) {
#pragma unroll
    for (int o = 32; o > 0; o >>= 1) v += __shfl_xor(v, o);
    return v;
}

// One block = 64 queries of one batch vs ALL 4096 points (staged in LDS).
// threads: t = g*16 + qcol ; wave w covers groups [4w, 4w+4).
// lpt padded +1 float4 per 128 entries so the 4 groups in a wave read
// disjoint bank quads (broadcast within each 16-lane group).
__global__ __launch_bounds__(TPB) void fused_kernel(const float* __restrict__ pc,
                                                    float* __restrict__ bpart) {
    __shared__ float4 lpt[NPTS + G];
    __shared__ float  smin[NW][QPB];
    __shared__ float  scen[NW][3];

    int b    = blockIdx.x >> 6;        // batch
    int blkq = blockIdx.x & 63;        // query-block within batch
    int iq0  = blkq * QPB;
    const float* p = pc + (size_t)b * NPTS * 3;
    int t = threadIdx.x;
    int lane = t & 63, w = t >> 6;

    // ---- stage batch: (x,y,z,|x|^2), padded ----
    for (int i = t; i < NPTS; i += TPB) {
        float x = p[3*i+0], y = p[3*i+1], z = p[3*i+2];
        lpt[i + (i >> 7)] = make_float4(x, y, z, fmaf(x, x, fmaf(y, y, z * z)));
    }
    __syncthreads();

    // ---- centroid partials (same order in every block of a batch) ----
    float sx = 0.f, sy = 0.f, sz = 0.f;
    for (int i = t; i < NPTS; i += TPB) {
        float4 q = lpt[i + (i >> 7)];
        sx += q.x; sy += q.y; sz += q.z;
    }
    sx = wave_sum(sx); sy = wave_sum(sy); sz = wave_sum(sz);
    if (lane == 0) { scen[w][0] = sx; scen[w][1] = sy; scen[w][2] = sz; }

    // ---- per-thread: 4 queries (prefolded -2x) vs group g's 128 points ----
    int qcol = t & (QCOLS - 1);
    int g    = t >> 4;
    float ax[IT], ay[IT], az[IT], m[IT];
#pragma unroll
    for (int k = 0; k < IT; ++k) {
        int iq = iq0 + qcol * IT + k;
        float4 q = lpt[iq + (iq >> 7)];
        ax[k] = -2.f * q.x; ay[k] = -2.f * q.y; az[k] = -2.f * q.z;
        m[k] = 1e30f;
    }
    const float4* gp = &lpt[g * (JG + 1)];

    int gd = blkq >> 1;                // group containing this block's queries
    int wd = blkq >> 3;                // wave containing that group
    if (w == wd) {                     // wave-uniform diagonal branch
        int idl[IT];
#pragma unroll
        for (int k = 0; k < IT; ++k)
            idl[k] = (g == gd) ? (iq0 + qcol * IT + k - gd * JG) : -1;
#pragma unroll 4
        for (int j = 0; j < JG; ++j) {
            float4 q = gp[j];
#pragma unroll
            for (int k = 0; k < IT; ++k) {
                float e = fmaf(ax[k], q.x, fmaf(ay[k], q.y, fmaf(az[k], q.z, q.w)));
                m[k] = fminf(m[k], (j == idl[k]) ? 1e30f : e);
            }
        }
    } else {
#pragma unroll 8
        for (int j = 0; j < JG; j += 2) {      // paired -> v_min3
            float4 q0 = gp[j], q1 = gp[j+1];
#pragma unroll
            for (int k = 0; k < IT; ++k) {
                float e0 = fmaf(ax[k], q0.x, fmaf(ay[k], q0.y, fmaf(az[k], q0.z, q0.w)));
                float e1 = fmaf(ax[k], q1.x, fmaf(ay[k], q1.y, fmaf(az[k], q1.z, q1.w)));
                m[k] = fminf(fminf(m[k], e0), e1);
            }
        }
    }

    // ---- min across the wave's 4 groups (lanes g*16+qcol: xor 16,32) ----
#pragma unroll
    for (int k = 0; k < IT; ++k) {
        m[k] = fminf(m[k], __shfl_xor(m[k], 16));
        m[k] = fminf(m[k], __shfl_xor(m[k], 32));
    }
    if (lane < QCOLS) {
#pragma unroll
        for (int k = 0; k < IT; ++k) smin[w][qcol * IT + k] = m[k];
    }
    __syncthreads();

    // ---- wave 0: min across 8 waves, exp, variance terms, block partials ----
    if (t < QPB) {
        float cx = 0.f, cy = 0.f, cz = 0.f;
#pragma unroll
        for (int ww = 0; ww < NW; ++ww) {
            cx += scen[ww][0]; cy += scen[ww][1]; cz += scen[ww][2];
        }
        cx *= (1.f / NPTS); cy *= (1.f / NPTS); cz *= (1.f / NPTS);

        float mm = smin[0][t];
#pragma unroll
        for (int ww = 1; ww < NW; ++ww) mm = fminf(mm, smin[ww][t]);

        int iq = iq0 + t;
        float4 q = lpt[iq + (iq >> 7)];
        float es = __expf(-5.f * fmaxf(q.w + mm, 0.f));   // clamp commutes with min

        float dx = q.x - cx, dy = q.y - cy, dz = q.z - cz;
        float d2 = fmaf(dx, dx, fmaf(dy, dy, dz * dz));
        float s1 = sqrtf(d2);

        es = wave_sum(es);
        float S1 = wave_sum(s1);
        float S2 = wave_sum(d2);
        if (t == 0) {
            bpart[blockIdx.x * 3 + 0] = S1;
            bpart[blockIdx.x * 3 + 1] = S2;
            bpart[blockIdx.x * 3 + 2] = es;
        }
    }
}

// wave w reduces batch w's 64 block-partials; lane0s combine via LDS.
__global__ __launch_bounds__(256) void finish_kernel(const float* __restrict__ bpart,
                                                     float* __restrict__ out) {
    __shared__ float svar[NB], ses[NB];
    int t = threadIdx.x;
    int w = t >> 6;                    // batch
    float s1 = bpart[t*3+0], s2 = bpart[t*3+1], es = bpart[t*3+2];
    s1 = wave_sum(s1); s2 = wave_sum(s2); es = wave_sum(es);
    if ((t & 63) == 0) {
        svar[w] = (s2 - s1 * s1 * (1.f / NPTS)) * (1.f / (NPTS - 1));
        ses[w]  = es;
    }
    __syncthreads();
    if (t == 0) {
        float vs = 0.f, et = 0.f;
#pragma unroll
        for (int bb = 0; bb < NB; ++bb) { vs += svar[bb]; et += ses[bb]; }
        out[0] = vs * (1.f / NB) + et * (1.f / BN);
    }
}

extern "C" void kernel_launch(void* const* d_in, const int* in_sizes, int n_in,
                              void* d_out, int out_size, void* d_ws, size_t ws_size,
                              hipStream_t stream) {
    const float* pc = (const float*)d_in[0];
    float* out   = (float*)d_out;
    float* bpart = (float*)d_ws;       // NBLK*3 floats = 3 KB

    fused_kernel<<<NBLK, TPB, 0, stream>>>(pc, bpart);
    finish_kernel<<<1, 256, 0, stream>>>(bpart, out);
}